// Round 1
// baseline (1209.339 us; speedup 1.0000x reference)
//
#include <hip/hip_runtime.h>
#include <math.h>

#define T_TOK 16384
#define HID   4096
#define NEXP  64
#define TPB   256   // tokens per block (== threads per block, 1 token/thread)
#define HK    16    // h-chunk staged in LDS per iteration

// Kernel A: partial logits. Block (tb, s) computes, for 256 tokens, the dot
// products over h-range [s*Hc, (s+1)*Hc) against all 64 expert rows.
// partial layout: [s][t][e]  (contiguous 64 floats per (s,t))
__global__ __launch_bounds__(256, 2)
void router_gemm_partial(const float* __restrict__ x,
                         const float* __restrict__ w,
                         float* __restrict__ partial, int NS) {
  __shared__ float Xs[TPB * (HK + 1)];  // +1 pad: bank = (17t+h)%32, 2-way max
  const int tid = threadIdx.x;
  const int nTb = T_TOK / TPB;          // 64
  const int tb  = blockIdx.x % nTb;
  const int s   = blockIdx.x / nTb;
  const int Hc  = HID / NS;
  const int h0  = s * Hc;
  const int t   = tb * TPB + tid;

  float acc[NEXP];
#pragma unroll
  for (int e = 0; e < NEXP; ++e) acc[e] = 0.f;

  for (int hc = 0; hc < Hc; hc += HK) {
    const int base = h0 + hc;
    __syncthreads();  // previous iteration's LDS reads done before overwrite
#pragma unroll
    for (int k = 0; k < HK; ++k) {
      int flat = tid + k * TPB;       // 0..4095, coalesced along hh
      int tt = flat >> 4;             // flat / HK
      int hh = flat & (HK - 1);       // flat % HK
      Xs[tt * (HK + 1) + hh] = x[(size_t)(tb * TPB + tt) * HID + base + hh];
    }
    __syncthreads();

    float xs[HK];
#pragma unroll
    for (int h = 0; h < HK; ++h) xs[h] = Xs[tid * (HK + 1) + h];

    const float* wb = w + base;       // wave-uniform -> scalar loads
#pragma unroll
    for (int e0 = 0; e0 < NEXP; e0 += 4) {
#pragma unroll
      for (int h = 0; h < HK; ++h) {
        acc[e0 + 0] = fmaf(xs[h], wb[(size_t)(e0 + 0) * HID + h], acc[e0 + 0]);
        acc[e0 + 1] = fmaf(xs[h], wb[(size_t)(e0 + 1) * HID + h], acc[e0 + 1]);
        acc[e0 + 2] = fmaf(xs[h], wb[(size_t)(e0 + 2) * HID + h], acc[e0 + 2]);
        acc[e0 + 3] = fmaf(xs[h], wb[(size_t)(e0 + 3) * HID + h], acc[e0 + 3]);
      }
    }
  }

  float4* out = (float4*)(partial + ((size_t)s * T_TOK + t) * NEXP);
#pragma unroll
  for (int e4 = 0; e4 < NEXP / 4; ++e4)
    out[e4] = make_float4(acc[4 * e4], acc[4 * e4 + 1],
                          acc[4 * e4 + 2], acc[4 * e4 + 3]);
}

// Kernel B: one wave per token, lane = expert. Reduce NS partials, write
// logits, softmax-free top-8 (denominator cancels in renorm), write
// scores + indices (indices stored as float values; harness reads f32).
__global__ __launch_bounds__(256)
void router_topk(const float* __restrict__ partial,
                 float* __restrict__ logits_out,
                 float* __restrict__ scores_out,
                 float* __restrict__ idx_out, int NS) {
  const int lane = threadIdx.x & 63;
  const int wid  = threadIdx.x >> 6;
  const int t    = blockIdx.x * 4 + wid;

  float l = 0.f;
  for (int s = 0; s < NS; ++s)
    l += partial[((size_t)s * T_TOK + t) * NEXP + lane];  // coalesced 256B
  logits_out[(size_t)t * NEXP + lane] = l;

  // wave max for numerics
  float m = l;
#pragma unroll
  for (int off = 32; off >= 1; off >>= 1)
    m = fmaxf(m, __shfl_xor(m, off, 64));
  float p = __expf(l - m);

  // top-8 on logits (exact ordering; softmax is monotonic), ties -> lower idx
  float v = l;
  float myscore = 0.f, myidx = 0.f, ssum = 0.f;
#pragma unroll
  for (int k = 0; k < 8; ++k) {
    float bv = v; int bi = lane;
#pragma unroll
    for (int off = 32; off >= 1; off >>= 1) {
      float ov = __shfl_xor(bv, off, 64);
      int   oi = __shfl_xor(bi, off, 64);
      if (ov > bv || (ov == bv && oi < bi)) { bv = ov; bi = oi; }
    }
    float pw = __shfl(p, bi, 64);   // exp value of winner
    ssum += pw;
    if (lane == k)  { myscore = pw; myidx = (float)bi; }
    if (lane == bi) v = -INFINITY;
  }
  if (lane < 8) {
    scores_out[(size_t)t * 8 + lane] = myscore / ssum;
    idx_out[(size_t)t * 8 + lane]    = myidx;
  }
}

extern "C" void kernel_launch(void* const* d_in, const int* in_sizes, int n_in,
                              void* d_out, int out_size, void* d_ws, size_t ws_size,
                              hipStream_t stream) {
  const float* x = (const float*)d_in[0];   // [16384, 4096]
  const float* w = (const float*)d_in[1];   // [64, 4096]
  float* out    = (float*)d_out;
  float* logits = out;                                   // [T,64]
  float* scores = out + (size_t)T_TOK * NEXP;            // [T,8]
  float* idxo   = scores + (size_t)T_TOK * 8;            // [T,8]
  float* partial = (float*)d_ws;

  size_t per = (size_t)T_TOK * NEXP * sizeof(float);     // 4.2 MB per split
  int NS = (ws_size >= 8 * per) ? 8 :
           (ws_size >= 4 * per) ? 4 :
           (ws_size >= 2 * per) ? 2 : 1;

  hipLaunchKernelGGL(router_gemm_partial,
                     dim3((T_TOK / TPB) * NS), dim3(TPB), 0, stream,
                     x, w, partial, NS);
  hipLaunchKernelGGL(router_topk,
                     dim3(T_TOK / 4), dim3(256), 0, stream,
                     partial, logits, scores, idxo, NS);
}

// Round 3
// 457.302 us; speedup vs baseline: 2.6445x; 2.6445x over previous
//
#include <hip/hip_runtime.h>
#include <math.h>

#define T_TOK  16384
#define HID    4096
#define NEXP   64
#define KSPLIT 4
#define KRANGE (HID / KSPLIT)   // 1024
#define NCHUNK (KRANGE / 32)    // 32 K-chunks of 32

typedef __attribute__((ext_vector_type(8))) short short8;
typedef __attribute__((ext_vector_type(4))) float float4v;

// d_ws: partial [KSPLIT][T_TOK][NEXP] f32 (16.8MB), then wh/wm/wl u16 (3x512KB)
#define PART_ELEMS ((size_t)KSPLIT * T_TOK * NEXP)
#define WHALF      ((size_t)NEXP * HID)

__device__ __forceinline__ unsigned short rne_bf16(float f) {
  unsigned u = __float_as_uint(f);
  unsigned r = u + 0x7FFFu + ((u >> 16) & 1u);
  return (unsigned short)(r >> 16);
}
__device__ __forceinline__ float bf16_f(unsigned short h) {
  return __uint_as_float(((unsigned)h) << 16);
}

// 3-way bf16 split of w: f = hi+mid+lo + O(2^-26 |f|). Subtractions exact
// (Sterbenz), RNE rounding at each stage.
__global__ void w_convert3(const float* __restrict__ w,
                           unsigned short* __restrict__ wh,
                           unsigned short* __restrict__ wm,
                           unsigned short* __restrict__ wl) {
  int t = blockIdx.x * 256 + threadIdx.x;
#pragma unroll
  for (int j = 0; j < 4; ++j) {
    int idx = t + j * 65536;
    float f = w[idx];
    unsigned short h = rne_bf16(f);
    float r1 = f - bf16_f(h);
    unsigned short m = rne_bf16(r1);
    float r2 = r1 - bf16_f(m);
    wh[idx] = h; wm[idx] = m; wl[idx] = rne_bf16(r2);
  }
}

// Wave = 32 tokens x 64 experts x K-range 1024. A (x) streamed from HBM with
// distance-2 register prefetch (4 buffers); B (w splits) from L2, half-tile
// (2 n-tiles) pipelined. 6 MFMA product terms per tile for f32-grade logits.
__global__ __launch_bounds__(256, 2)
void router_gemm(const float* __restrict__ x,
                 const unsigned short* __restrict__ wh,
                 const unsigned short* __restrict__ wm,
                 const unsigned short* __restrict__ wl,
                 float* __restrict__ partial) {
  const int lane = threadIdx.x & 63;
  const int wid  = threadIdx.x >> 6;
  const int W    = blockIdx.x * 4 + wid;       // 0..2047
  const int ks   = W & (KSPLIT - 1);
  const int t0   = (W >> 2) * 32;
  const int r    = lane & 15;
  const int q    = lane >> 4;
  const int k0   = ks * KRANGE + q * 8;

  const float* pa0 = x + (size_t)(t0 + r) * HID + k0;
  const float* pa1 = pa0 + (size_t)16 * HID;
  const unsigned short* pb[3];
  pb[0] = wh + (size_t)r * HID + k0;
  pb[1] = wm + (size_t)r * HID + k0;
  pb[2] = wl + (size_t)r * HID + k0;

  float4v acc[2][4];
#pragma unroll
  for (int m = 0; m < 2; ++m)
#pragma unroll
    for (int n = 0; n < 4; ++n) acc[m][n] = (float4v)(0.f);

  float4 araw[4][2][2];     // [buf][Mtile][half-of-8]
  short8 ah[2], am_[2], al[2];
  short8 Bb[2][2][3];       // [half][n_local][split]

#define LOADA(buf, c) do {                                                   \
    const int _o = (c) * 32;                                                 \
    araw[buf][0][0] = *(const float4*)(pa0 + _o);                            \
    araw[buf][0][1] = *(const float4*)(pa0 + _o + 4);                        \
    araw[buf][1][0] = *(const float4*)(pa1 + _o);                            \
    araw[buf][1][1] = *(const float4*)(pa1 + _o + 4);                        \
  } while (0)

#define LOADB(half, c) do {                                                  \
    const int _o = (c) * 32;                                                 \
    _Pragma("unroll")                                                        \
    for (int _nl = 0; _nl < 2; ++_nl) {                                      \
      const size_t _nb = (size_t)((half) * 2 + _nl) * 16 * HID + _o;         \
      _Pragma("unroll")                                                      \
      for (int _s = 0; _s < 3; ++_s)                                         \
        Bb[half][_nl][_s] = *(const short8*)(pb[_s] + _nb);                  \
    }                                                                        \
  } while (0)

#define SPLITA(buf) do {                                                     \
    _Pragma("unroll")                                                        \
    for (int _m = 0; _m < 2; ++_m) {                                         \
      const float4 _v0 = araw[buf][_m][0], _v1 = araw[buf][_m][1];           \
      float _f[8] = {_v0.x,_v0.y,_v0.z,_v0.w,_v1.x,_v1.y,_v1.z,_v1.w};       \
      _Pragma("unroll")                                                      \
      for (int _j = 0; _j < 8; ++_j) {                                       \
        unsigned short _h = rne_bf16(_f[_j]);                                \
        float _r1 = _f[_j] - bf16_f(_h);                                     \
        unsigned short _mm = rne_bf16(_r1);                                  \
        float _r2 = _r1 - bf16_f(_mm);                                       \
        ah[_m][_j] = (short)_h; am_[_m][_j] = (short)_mm;                    \
        al[_m][_j] = (short)rne_bf16(_r2);                                   \
      }                                                                      \
    }                                                                        \
  } while (0)

#define MFMAH(half) do {                                                     \
    _Pragma("unroll")                                                        \
    for (int _nl = 0; _nl < 2; ++_nl) {                                      \
      const int _n = (half) * 2 + _nl;                                       \
      const short8 _BH = Bb[half][_nl][0];                                   \
      const short8 _BM = Bb[half][_nl][1];                                   \
      const short8 _BL = Bb[half][_nl][2];                                   \
      _Pragma("unroll")                                                      \
      for (int _m = 0; _m < 2; ++_m) {                                       \
        float4v _a = acc[_m][_n];                                            \
        _a = __builtin_amdgcn_mfma_f32_16x16x32_bf16(al[_m],  _BH, _a,0,0,0);\
        _a = __builtin_amdgcn_mfma_f32_16x16x32_bf16(ah[_m],  _BL, _a,0,0,0);\
        _a = __builtin_amdgcn_mfma_f32_16x16x32_bf16(am_[_m], _BM, _a,0,0,0);\
        _a = __builtin_amdgcn_mfma_f32_16x16x32_bf16(am_[_m], _BH, _a,0,0,0);\
        _a = __builtin_amdgcn_mfma_f32_16x16x32_bf16(ah[_m],  _BM, _a,0,0,0);\
        _a = __builtin_amdgcn_mfma_f32_16x16x32_bf16(ah[_m],  _BH, _a,0,0,0);\
        acc[_m][_n] = _a;                                                    \
      }                                                                      \
    }                                                                        \
  } while (0)

  LOADA(0, 0); LOADA(1, 1);
  LOADB(0, 0);
  for (int cc = 0; cc < NCHUNK; cc += 4) {
    if (cc + 2 < NCHUNK) LOADA(2, cc + 2);
    SPLITA(0); LOADB(1, cc);     MFMAH(0);
    LOADB(0, cc + 1);            MFMAH(1);

    if (cc + 3 < NCHUNK) LOADA(3, cc + 3);
    SPLITA(1); LOADB(1, cc + 1); MFMAH(0);
    LOADB(0, cc + 2);            MFMAH(1);

    if (cc + 4 < NCHUNK) LOADA(0, cc + 4);
    SPLITA(2); LOADB(1, cc + 2); MFMAH(0);
    LOADB(0, cc + 3);            MFMAH(1);

    if (cc + 5 < NCHUNK) LOADA(1, cc + 5);
    SPLITA(3); LOADB(1, cc + 3); MFMAH(0);
    if (cc + 4 < NCHUNK) LOADB(0, cc + 4);
    MFMAH(1);
  }
#undef LOADA
#undef LOADB
#undef SPLITA
#undef MFMAH

  // D[row=(lane>>4)*4+reg][col=lane&15]  (m89/m91-verified)
  float* po = partial + ((size_t)ks * T_TOK + t0) * NEXP;
#pragma unroll
  for (int m = 0; m < 2; ++m)
#pragma unroll
    for (int n = 0; n < 4; ++n)
#pragma unroll
      for (int rr = 0; rr < 4; ++rr)
        po[(size_t)(m * 16 + q * 4 + rr) * NEXP + n * 16 + r] = acc[m][n][rr];
}

// One wave per token, lane = expert. Reduce KSPLIT partials, write logits,
// top-8 on logits (softmax monotone; denominator cancels in renorm),
// ties -> lowest index (lax.top_k semantics).
__global__ __launch_bounds__(256)
void router_topk(const float* __restrict__ partial,
                 float* __restrict__ logits_out,
                 float* __restrict__ scores_out,
                 float* __restrict__ idx_out) {
  const int lane = threadIdx.x & 63;
  const int wid  = threadIdx.x >> 6;
  const int t    = blockIdx.x * 4 + wid;

  float ps[KSPLIT];
#pragma unroll
  for (int s = 0; s < KSPLIT; ++s)
    ps[s] = partial[((size_t)s * T_TOK + t) * NEXP + lane];
  float l = (ps[0] + ps[1]) + (ps[2] + ps[3]);
  logits_out[(size_t)t * NEXP + lane] = l;

  float m = l;
#pragma unroll
  for (int off = 32; off >= 1; off >>= 1)
    m = fmaxf(m, __shfl_xor(m, off, 64));
  float p = __expf(l - m);

  float v = l;
  float myscore = 0.f, myidx = 0.f, ssum = 0.f;
#pragma unroll
  for (int k = 0; k < 8; ++k) {
    float bv = v; int bi = lane;
#pragma unroll
    for (int off = 32; off >= 1; off >>= 1) {
      float ov = __shfl_xor(bv, off, 64);
      int   oi = __shfl_xor(bi, off, 64);
      if (ov > bv || (ov == bv && oi < bi)) { bv = ov; bi = oi; }
    }
    float pw = __shfl(p, bi, 64);
    ssum += pw;
    if (lane == k)  { myscore = pw; myidx = (float)bi; }
    if (lane == bi) v = -INFINITY;
  }
  if (lane < 8) {
    scores_out[(size_t)t * 8 + lane] = myscore / ssum;
    idx_out[(size_t)t * 8 + lane]    = myidx;
  }
}

extern "C" void kernel_launch(void* const* d_in, const int* in_sizes, int n_in,
                              void* d_out, int out_size, void* d_ws, size_t ws_size,
                              hipStream_t stream) {
  const float* x = (const float*)d_in[0];   // [16384, 4096]
  const float* w = (const float*)d_in[1];   // [64, 4096]
  float* out    = (float*)d_out;
  float* logits = out;                                   // [T,64]
  float* scores = out + (size_t)T_TOK * NEXP;            // [T,8]
  float* idxo   = scores + (size_t)T_TOK * 8;            // [T,8]

  float* partial = (float*)d_ws;
  unsigned short* wh = (unsigned short*)((char*)d_ws + PART_ELEMS * sizeof(float));
  unsigned short* wm = wh + WHALF;
  unsigned short* wl = wm + WHALF;

  hipLaunchKernelGGL(w_convert3, dim3(256), dim3(256), 0, stream, w, wh, wm, wl);
  hipLaunchKernelGGL(router_gemm, dim3(2048 / 4), dim3(256), 0, stream,
                     x, wh, wm, wl, partial);
  hipLaunchKernelGGL(router_topk, dim3(T_TOK / 4), dim3(256), 0, stream,
                     partial, logits, scores, idxo);
}